// Round 13
// baseline (331.255 us; speedup 1.0000x reference)
//
#include <hip/hip_runtime.h>

#define N_NODES 100000
#define N_EDGES 1600000
#define NBUCK 391          // 256 nodes per bucket (dst >> 8)
#define BCAP 4800          // expected 4096 +- 64; ~11 sigma headroom
#define CH 4096            // edges per multisplit chunk
#define NCHUNK ((N_EDGES + CH - 1) / CH)  // 391

typedef __attribute__((ext_vector_type(2))) _Float16 half2v;
typedef __attribute__((ext_vector_type(4))) _Float16 half4v;
typedef __attribute__((ext_vector_type(8))) _Float16 half8v;
typedef __attribute__((ext_vector_type(4))) float f32x4;

__device__ __forceinline__ float4 loadX4(const float* X, size_t idx) {
    return *(const float4*)(X + idx);
}
__device__ __forceinline__ float4 loadX4(const _Float16* X, size_t idx) {
    half4v h = *(const half4v*)(X + idx);
    return make_float4((float)h.x, (float)h.y, (float)h.z, (float)h.w);
}

// ---------------- counting-sort CSR build ----------------

__global__ __launch_bounds__(256) void zero_small(int* p, int n) {
    int i = blockIdx.x * blockDim.x + threadIdx.x;
    if (i < n) p[i] = 0;
}

// Pass A: multisplit edges into NBUCK per-bucket arrays of packed (dstlocal<<17|src).
__global__ __launch_bounds__(256) void multisplit(const int* __restrict__ src,
                                                  const int* __restrict__ dst,
                                                  int* cursor,
                                                  int* __restrict__ bucketed, int e) {
    __shared__ int cnt[NBUCK];
    __shared__ int basel[NBUCK];
    const int t = threadIdx.x;
    const int base_e = blockIdx.x * CH;

    int myS[16], myD[16];
    for (int i = t; i < NBUCK; i += 256) cnt[i] = 0;
    __syncthreads();

#pragma unroll
    for (int k = 0; k < 16; ++k) {
        int i = base_e + k * 256 + t;
        if (i < e) {
            myS[k] = src[i];
            myD[k] = dst[i];
            atomicAdd(&cnt[myD[k] >> 8], 1);
        } else {
            myD[k] = -1;
        }
    }
    __syncthreads();
    for (int i = t; i < NBUCK; i += 256) basel[i] = atomicAdd(&cursor[i], cnt[i]);
    __syncthreads();
    for (int i = t; i < NBUCK; i += 256) cnt[i] = 0;
    __syncthreads();

#pragma unroll
    for (int k = 0; k < 16; ++k) {
        if (myD[k] >= 0) {
            int b = myD[k] >> 8;
            int pos = basel[b] + atomicAdd(&cnt[b], 1);
            if (pos < BCAP)
                bucketed[(size_t)b * BCAP + pos] = ((myD[k] & 255) << 17) | myS[k];
        }
    }
}

// exclusive scan of NBUCK bucket sizes -> gbase[NBUCK+1]
__global__ __launch_bounds__(512) void bucket_scan(const int* __restrict__ cursor,
                                                   int* __restrict__ gbase) {
    __shared__ int sm[512];
    const int t = threadIdx.x;
    int v = (t < NBUCK) ? cursor[t] : 0;
    sm[t] = v;
    __syncthreads();
    for (int off = 1; off < 512; off <<= 1) {
        int u = (t >= off) ? sm[t - off] : 0;
        __syncthreads();
        sm[t] += u;
        __syncthreads();
    }
    if (t < NBUCK) gbase[t] = sm[t] - v;
    if (t == NBUCK - 1) gbase[NBUCK] = sm[t];
}

// Pass B: one 256-thread block per 256-node bucket.
__global__ __launch_bounds__(256) void build_csr(const int* __restrict__ bucketed,
                                                 const int* __restrict__ gbase,
                                                 int* __restrict__ row_ptr,
                                                 float* __restrict__ dinv,
                                                 int* __restrict__ csr_src, int n) {
    __shared__ int vals[BCAP];
    __shared__ int cnt[256];
    __shared__ int lcur[256];
    const int b = blockIdx.x;
    const int t = threadIdx.x;
    const int nb0 = b * 256;
    const int nn = min(256, n - nb0);
    const int gb = gbase[b];
    const int m = gbase[b + 1] - gb;

    cnt[t] = 0;
    __syncthreads();
    for (int i = t; i < m; i += 256) {
        int v = bucketed[(size_t)b * BCAP + i];
        vals[i] = v;
        atomicAdd(&cnt[v >> 17], 1);
    }
    __syncthreads();

    int deg = cnt[t];
    for (int off = 1; off < 256; off <<= 1) {
        int u = (t >= off) ? cnt[t - off] : 0;
        __syncthreads();
        cnt[t] += u;
        __syncthreads();
    }
    int offv = cnt[t] - deg;
    __syncthreads();
    cnt[t] = offv;
    lcur[t] = 0;
    if (t < nn) {
        row_ptr[nb0 + t] = gb + offv;
        dinv[nb0 + t] = rsqrtf((float)(deg + 1));
    }
    if (b == NBUCK - 1 && t == 0) row_ptr[n] = gb + m;
    __syncthreads();

    for (int i = t; i < m; i += 256) {
        int v = vals[i];
        int node = v >> 17;
        int pos = atomicAdd(&lcur[node], 1);
        csr_src[gb + cnt[node] + pos] = v & 0x1FFFF;
    }
}

// ---------------- W pre-transpose: Wt[n][k] = fp16(W[k][n]) ----------------

template <int K>
__global__ __launch_bounds__(256) void transpose_w(const float* __restrict__ W,
                                                   _Float16* __restrict__ Wt) {
    int i = blockIdx.x * 256 + threadIdx.x;
    if (i < K * 64) {
        int k = i >> 6, nn = i & 63;
        Wt[(size_t)nn * K + k] = (_Float16)W[i];
    }
}

// ---------------- MFMA GEMM: Y[N,64] = fp16(dinv * X[N,K] @ W) (R12) ----------------

__device__ __forceinline__ void stageX_rows(const float* X, _Float16* Xl, int t,
                                            int row0, int n, int K, int SP) {
    for (int i = t; i < 64 * K / 4; i += 256) {
        int r = i / (K / 4), c = (i % (K / 4)) * 4;
        int grow = min(row0 + r, n - 1);
        float4 v = *(const float4*)(X + (size_t)grow * K + c);
        half4v h = {(_Float16)v.x, (_Float16)v.y, (_Float16)v.z, (_Float16)v.w};
        *(half4v*)(Xl + r * SP + c) = h;
    }
}
__device__ __forceinline__ void stageX_rows(const _Float16* X, _Float16* Xl, int t,
                                            int row0, int n, int K, int SP) {
    for (int i = t; i < 64 * K / 8; i += 256) {
        int r = i / (K / 8), c = (i % (K / 8)) * 8;
        int grow = min(row0 + r, n - 1);
        *(half8v*)(Xl + r * SP + c) = *(const half8v*)(X + (size_t)grow * K + c);
    }
}

template <int K, typename XT>
__global__ __launch_bounds__(256) void gemm_mfma64(const XT* __restrict__ X,
                                                   const _Float16* __restrict__ Wt,
                                                   const float* __restrict__ dinv,
                                                   _Float16* __restrict__ Y, int n) {
    constexpr int SP = K + 8;
    __shared__ _Float16 Xl[64 * SP];
    __shared__ _Float16 Wl[64 * SP];
    const int t = threadIdx.x;
    const int wave = t >> 6, lane = t & 63;
    const int row0 = blockIdx.x * 64;
    const int m = lane & 15, quad = lane >> 4;

    for (int i = t; i < 64 * K / 8; i += 256) {
        int r = i / (K / 8), c = (i % (K / 8)) * 8;
        *(half8v*)(Wl + r * SP + c) = *(const half8v*)(Wt + (size_t)r * K + c);
    }
    stageX_rows(X, Xl, t, row0, n, K, SP);
    __syncthreads();

    f32x4 acc[4] = {{0,0,0,0},{0,0,0,0},{0,0,0,0},{0,0,0,0}};
#pragma unroll
    for (int k0 = 0; k0 < K; k0 += 32) {
        half8v a = *(const half8v*)(Xl + (wave * 16 + m) * SP + k0 + quad * 8);
#pragma unroll
        for (int ct = 0; ct < 4; ++ct) {
            half8v b = *(const half8v*)(Wl + (ct * 16 + m) * SP + k0 + quad * 8);
            acc[ct] = __builtin_amdgcn_mfma_f32_16x16x32_f16(a, b, acc[ct], 0, 0, 0);
        }
    }

    float dv[4];
#pragma unroll
    for (int r = 0; r < 4; ++r) {
        int row = row0 + wave * 16 + quad * 4 + r;
        dv[r] = dinv[min(row, n - 1)];
    }
#pragma unroll
    for (int ct = 0; ct < 4; ++ct) {
#pragma unroll
        for (int r = 0; r < 4; ++r) {
            int row = row0 + wave * 16 + quad * 4 + r;
            if (row < n)
                Y[(size_t)row * 64 + ct * 16 + m] = (_Float16)(dv[r] * acc[ct][r]);
        }
    }
}

// ---------------- VALU GEMM (layer 3, COUT=40) (R12) ----------------

template <int K, int COUT, typename XT>
__global__ __launch_bounds__(256) void gemm_rt(const XT* __restrict__ X,
                                               const float* __restrict__ W,
                                               const float* __restrict__ dinv,
                                               _Float16* __restrict__ Y, int n) {
    constexpr int KC = 64;
    constexpr int S = KC + 4;
    constexpr int NCH = K / KC;
    __shared__ float Xl[64 * S];
    __shared__ float Wl[KC * COUT];

    const int t = threadIdx.x;
    const int row0 = blockIdx.x * 64;
    const int cg = (t & 15) * 4;
    const int rg = (t >> 4) * 4;

    float acc[4][4] = {};

#pragma unroll
    for (int ch = 0; ch < NCH; ++ch) {
        const int k0 = ch * KC;
        for (int i = t; i < 64 * KC / 4; i += 256) {
            int r = i >> 4;
            int k = (i & 15) * 4;
            int grow = min(row0 + r, n - 1);
            *(float4*)(Xl + r * S + k) = loadX4(X, (size_t)grow * K + k0 + k);
        }
        for (int i = t; i < KC * COUT / 4; i += 256) {
            *(float4*)(Wl + i * 4) = *(const float4*)(W + (size_t)k0 * COUT + (size_t)i * 4);
        }
        __syncthreads();

        if (cg < COUT) {
#pragma unroll 4
            for (int k = 0; k < KC; ++k) {
                float4 w = *(const float4*)(Wl + k * COUT + cg);
                float x0 = Xl[(rg + 0) * S + k];
                float x1 = Xl[(rg + 1) * S + k];
                float x2 = Xl[(rg + 2) * S + k];
                float x3 = Xl[(rg + 3) * S + k];
                acc[0][0] += x0 * w.x; acc[0][1] += x0 * w.y; acc[0][2] += x0 * w.z; acc[0][3] += x0 * w.w;
                acc[1][0] += x1 * w.x; acc[1][1] += x1 * w.y; acc[1][2] += x1 * w.z; acc[1][3] += x1 * w.w;
                acc[2][0] += x2 * w.x; acc[2][1] += x2 * w.y; acc[2][2] += x2 * w.z; acc[2][3] += x2 * w.w;
                acc[3][0] += x3 * w.x; acc[3][1] += x3 * w.y; acc[3][2] += x3 * w.z; acc[3][3] += x3 * w.w;
            }
        }
        __syncthreads();
    }

    if (cg < COUT) {
#pragma unroll
        for (int r = 0; r < 4; ++r) {
            int row = row0 + rg + r;
            if (row < n) {
                float d = dinv[row];
                half4v o = { (_Float16)(d * acc[r][0]), (_Float16)(d * acc[r][1]),
                             (_Float16)(d * acc[r][2]), (_Float16)(d * acc[r][3]) };
                *(half4v*)(Y + (size_t)row * COUT + cg) = o;
            }
        }
    }
}

// ---------------- aggregation, COUT=64 (R12 structure) ----------------

template <bool RELU>
__global__ __launch_bounds__(256) void aggregate64b(const _Float16* __restrict__ tS,
                                                    const int* __restrict__ row_ptr,
                                                    const int* __restrict__ csr_src,
                                                    const float* __restrict__ dinv,
                                                    const float* __restrict__ bias,
                                                    _Float16* __restrict__ out, int n) {
    const int lane = threadIdx.x & 63;
    const int node = blockIdx.x * 4 + (threadIdx.x >> 6);
    if (node >= n) return;
    const int g = lane >> 3;
    const int c8 = lane & 7;
    const half8v* tS8 = (const half8v*)tS;

    const int beg = row_ptr[node];
    const int cnt = row_ptr[node + 1] - beg;

    half8v accA, accB;
#pragma unroll
    for (int i = 0; i < 8; ++i) { accA[i] = (_Float16)0; accB[i] = (_Float16)0; }

    for (int j0 = 0; j0 < cnt; j0 += 64) {
        const int m = min(64, cnt - j0);
        int sj = csr_src[beg + j0 + min(lane, m - 1)];

        int j = 0;
        for (; j + 16 <= m; j += 16) {
            int e0 = __shfl(sj, j + g);
            int e1 = __shfl(sj, j + 8 + g);
            half8v v0 = tS8[(size_t)e0 * 8 + c8];
            half8v v1 = tS8[(size_t)e1 * 8 + c8];
            accA += v0;
            accB += v1;
        }
        for (; j + 8 <= m; j += 8) {
            int e0 = __shfl(sj, j + g);
            accA += tS8[(size_t)e0 * 8 + c8];
        }
        if (j < m) {
            int idx = j + g;
            int e0 = __shfl(sj, min(idx, m - 1));
            half8v v = tS8[(size_t)e0 * 8 + c8];
            if (idx < m) accB += v;
        }
    }

    float acc[8];
#pragma unroll
    for (int i = 0; i < 8; ++i) acc[i] = (float)accA[i] + (float)accB[i];
#pragma unroll
    for (int off = 8; off < 64; off <<= 1) {
#pragma unroll
        for (int i = 0; i < 8; ++i) acc[i] += __shfl_xor(acc[i], off);
    }

    if (lane < 8) {
        half8v selfh = tS8[(size_t)node * 8 + c8];
        float4 b0 = *(const float4*)(bias + c8 * 8);
        float4 b1 = *(const float4*)(bias + c8 * 8 + 4);
        const float bb[8] = {b0.x, b0.y, b0.z, b0.w, b1.x, b1.y, b1.z, b1.w};
        float d = dinv[node];
        half8v o;
#pragma unroll
        for (int i = 0; i < 8; ++i) {
            float v = bb[i] + d * (acc[i] + (float)selfh[i]);
            if (RELU) v = fmaxf(v, 0.0f);
            o[i] = (_Float16)v;
        }
        ((half8v*)out)[(size_t)node * 8 + c8] = o;
    }
}

// ---------------- aggregation, COUT=40, half8 12-group version ----------------
// Row = 40 halves = 5 half8 chunks (80B). 12 groups x 5 lanes (lanes 60-63 idle):
// one wave-issue covers 12 edges x 16B. Packed-fp16 accumulate; log-shfl group
// reduction (+30,+15,+5,+10 — lanes<30/<15/<5 only pull already-correct lanes).

__global__ __launch_bounds__(256) void aggregate40b(const _Float16* __restrict__ tS,
                                                    const int* __restrict__ row_ptr,
                                                    const int* __restrict__ csr_src,
                                                    const float* __restrict__ dinv,
                                                    const float* __restrict__ bias,
                                                    float* __restrict__ out, int n) {
    const int lane = threadIdx.x & 63;
    const int node = blockIdx.x * 4 + (threadIdx.x >> 6);
    if (node >= n) return;
    const int g = lane / 5;          // 0..11 active, 12 = idle (lanes 60-63)
    const int c5 = lane - 5 * g;     // chunk 0..4
    const bool act = (g < 12);
    const half8v* tS8 = (const half8v*)tS;

    const int beg = row_ptr[node];
    const int cnt = row_ptr[node + 1] - beg;

    half8v accA, accB;
#pragma unroll
    for (int i = 0; i < 8; ++i) { accA[i] = (_Float16)0; accB[i] = (_Float16)0; }

    for (int j0 = 0; j0 < cnt; j0 += 64) {
        const int m = min(64, cnt - j0);
        int sj = csr_src[beg + j0 + min(lane, m - 1)];

        int j = 0;
        for (; j + 24 <= m; j += 24) {
            int e0 = __shfl(sj, j + g);
            int e1 = __shfl(sj, j + 12 + g);
            half8v v0 = tS8[(size_t)e0 * 5 + c5];
            half8v v1 = tS8[(size_t)e1 * 5 + c5];
            if (act) { accA += v0; accB += v1; }
        }
        for (; j + 12 <= m; j += 12) {
            int e0 = __shfl(sj, j + g);
            half8v v0 = tS8[(size_t)e0 * 5 + c5];
            if (act) accA += v0;
        }
        if (j < m) {
            int idx = j + g;
            int e0 = __shfl(sj, min(idx, m - 1));
            half8v v = tS8[(size_t)e0 * 5 + c5];
            if (act && idx < m) accB += v;
        }
    }

    float acc[8];
#pragma unroll
    for (int i = 0; i < 8; ++i) acc[i] = (float)accA[i] + (float)accB[i];
    // reduce 12 groups -> group 0 (lanes 0..4)
#pragma unroll
    for (int i = 0; i < 8; ++i) {
        acc[i] += __shfl(acc[i], lane + 30);   // g += g+6   (valid for lanes<30)
        acc[i] += __shfl(acc[i], lane + 15);   // g += g+3   (valid for lanes<15)
        float p1 = __shfl(acc[i], lane + 5);   // g1
        float p2 = __shfl(acc[i], lane + 10);  // g2
        acc[i] += p1 + p2;                     // valid for lanes<5
    }

    if (lane < 5) {
        half8v selfh = tS8[(size_t)node * 5 + c5];
        float4 b0 = *(const float4*)(bias + c5 * 8);
        float4 b1 = *(const float4*)(bias + c5 * 8 + 4);
        const float bb[8] = {b0.x, b0.y, b0.z, b0.w, b1.x, b1.y, b1.z, b1.w};
        float d = dinv[node];
        float ov[8];
#pragma unroll
        for (int i = 0; i < 8; ++i)
            ov[i] = bb[i] + d * (acc[i] + (float)selfh[i]);
        float4* o4 = (float4*)(out + (size_t)node * 40 + c5 * 8);
        o4[0] = make_float4(ov[0], ov[1], ov[2], ov[3]);
        o4[1] = make_float4(ov[4], ov[5], ov[6], ov[7]);
    }
}

// ---------------- launch ----------------

extern "C" void kernel_launch(void* const* d_in, const int* in_sizes, int n_in,
                              void* d_out, int out_size, void* d_ws, size_t ws_size,
                              hipStream_t stream) {
    const float* x  = (const float*)d_in[0];
    const int*   ei = (const int*)d_in[1];
    const int*   src = ei;
    const int*   dst = ei + N_EDGES;
    const float* W1 = (const float*)d_in[2];
    const float* b1 = (const float*)d_in[3];
    const float* W2 = (const float*)d_in[4];
    const float* b2 = (const float*)d_in[5];
    const float* W3 = (const float*)d_in[6];
    const float* b3 = (const float*)d_in[7];
    float* out = (float*)d_out;

    const int N = N_NODES, E = N_EDGES;

    char* p = (char*)d_ws;
    int*   cursor   = (int*)p;              p += 512 * 4;
    int*   gbase    = (int*)p;              p += 512 * 4;
    float* dinv     = (float*)p;            p += (size_t)N * 4;
    int*   row_ptr  = (int*)p;              p += (size_t)(N + 4) * 4;
    int*   bucketed = (int*)p;              p += (size_t)NBUCK * BCAP * 4;
    int*   csr_src  = (int*)p;              p += (size_t)E * 4;
    p = (char*)(((size_t)p + 15) & ~(size_t)15);
    _Float16* Wt1   = (_Float16*)p;         p += (size_t)64 * 128 * 2;
    _Float16* Wt2   = (_Float16*)p;         p += (size_t)64 * 64 * 2;
    _Float16* bufA  = (_Float16*)p;         p += (size_t)N * 64 * 2;  // fp16 tS
    p = (char*)(((size_t)p + 15) & ~(size_t)15);
    _Float16* bufB  = (_Float16*)p;         p += (size_t)N * 64 * 2;  // fp16 h

    // ---- counting-sort CSR build + W pre-transpose ----
    zero_small<<<2, 256, 0, stream>>>(cursor, NBUCK);
    transpose_w<128><<<32, 256, 0, stream>>>(W1, Wt1);
    transpose_w<64><<<16, 256, 0, stream>>>(W2, Wt2);
    multisplit<<<NCHUNK, 256, 0, stream>>>(src, dst, cursor, bucketed, E);
    bucket_scan<<<1, 512, 0, stream>>>(cursor, gbase);
    build_csr<<<NBUCK, 256, 0, stream>>>(bucketed, gbase, row_ptr, dinv, csr_src, N);

    const int aggGrid = (N + 3) / 4;
    const int gemmGrid = (N + 63) / 64;

    // layer 1: x fp32 -> tS fp16 (MFMA); aggregate+relu -> h fp16
    gemm_mfma64<128, float><<<gemmGrid, 256, 0, stream>>>(x, Wt1, dinv, bufA, N);
    aggregate64b<true><<<aggGrid, 256, 0, stream>>>(bufA, row_ptr, csr_src, dinv, b1, bufB, N);

    // layer 2: h fp16 -> tS fp16 (MFMA); aggregate+relu -> h fp16
    gemm_mfma64<64, _Float16><<<gemmGrid, 256, 0, stream>>>(bufB, Wt2, dinv, bufA, N);
    aggregate64b<true><<<aggGrid, 256, 0, stream>>>(bufA, row_ptr, csr_src, dinv, b2, bufB, N);

    // layer 3: h fp16 -> tS40 fp16 (VALU); aggregate -> out fp32
    gemm_rt<64, 40, _Float16><<<gemmGrid, 256, 0, stream>>>(bufB, W3, dinv, bufA, N);
    aggregate40b<<<aggGrid, 256, 0, stream>>>(bufA, row_ptr, csr_src, dinv, b3, out, N);
}